// Round 7
// baseline (309.461 us; speedup 1.0000x reference)
//
#include <hip/hip_runtime.h>
#include <hip/hip_bf16.h>

// B=16, S=2048, D=512 attention with sum-pool over queries.
// out[b] = ((sum_q softmax(X M X^T * scale)[q,:]) @ X_b) @ Wv,  M = Wq Wk^T.
// log2(e)/sqrt(D) folded into M so exponentials are native exp2.
// E = exp2(scores) stored fp8 (HW e4m3), tiled [b][qt][kt][col128][row4(32)].
// passAE: 16x16x32 core (R5-proven: 111us, VGPR 76, conflicts 2.1M epilogue-only).
// 32x32x16 core REGRESSED (R6: 11.5M conflicts, 139us) — even-row lanes hit only
// 2/8 bank groups under the >>1 slot swizzle. Do not reintroduce without a
// verified bank mapping.
// XCD swizzle: blockLinear%8 -> XCD; each XCD streams 2 batches (4MB = its L2).

#define S_LEN 2048
#define D_DIM 512
#define BATCH 16

typedef short bf16x8 __attribute__((ext_vector_type(8)));
typedef float f32x4 __attribute__((ext_vector_type(4)));

typedef __attribute__((address_space(3))) void lds_void_t;
typedef const __attribute__((address_space(1))) void gbl_void_t;

__device__ __forceinline__ void async_copy16(const void* g, void* l) {
  __builtin_amdgcn_global_load_lds((gbl_void_t*)g, (lds_void_t*)l, 16, 0, 0);
}

__device__ __forceinline__ unsigned short f2bf(float f) {
  unsigned u = __float_as_uint(f);
  u += 0x7fff + ((u >> 16) & 1);   // RNE
  return (unsigned short)(u >> 16);
}
__device__ __forceinline__ float bf2f(unsigned short h) {
  return __uint_as_float((unsigned)h << 16);
}

#if __has_builtin(__builtin_amdgcn_cvt_pk_fp8_f32) && __has_builtin(__builtin_amdgcn_cvt_f32_fp8)
#define HAVE_FP8CVT 1
#else
#define HAVE_FP8CVT 0
#endif

__device__ __forceinline__ unsigned enc8(float x) {
  unsigned u = __float_as_uint(x);
  unsigned t = (u + 0x7FFFFu + ((u >> 20) & 1u)) >> 20;
  int b = (int)t - 0x3C0;
  b = b < 0 ? 0 : (b > 127 ? 127 : b);
  return (unsigned)b;
}
__device__ __forceinline__ float dec8(unsigned b) {
  return b ? __uint_as_float((b + 0x3C0u) << 20) : 0.0f;
}

__device__ __forceinline__ unsigned pack4_fp8(float e0, float e1, float e2, float e3) {
#if HAVE_FP8CVT
  unsigned dw = (unsigned)__builtin_amdgcn_cvt_pk_fp8_f32(e0, e1, 0, false);
  dw = (unsigned)__builtin_amdgcn_cvt_pk_fp8_f32(e2, e3, (int)dw, true);
  return dw;
#else
  return enc8(e0) | (enc8(e1) << 8) | (enc8(e2) << 16) | (enc8(e3) << 24);
#endif
}

// ---------------- NT GEMM core (16x16x32): C(128x128) = A*B^T, bf16, fp32 acc.
// BK=32, rotate swizzle -> ds_read_b128 conflict-free (R3/R5 verified).
__device__ __forceinline__ void gemm_core_nt(
    const unsigned short* __restrict__ A, long lda,
    const unsigned short* __restrict__ B, long ldb,
    int K, unsigned short* As, unsigned short* Bs, f32x4 acc[4][4])
{
  const int tid  = threadIdx.x;
  const int lane = tid & 63;
  const int w    = tid >> 6;
  const int wm   = w >> 1, wn = w & 1;
  const int r16  = lane & 15;
  const int kq   = lane >> 4;

  const int j0 = w * 64 + lane;
  const int j1 = (w + 4) * 64 + lane;
  const int r0 = j0 >> 2, cc0 = (((j0 & 3) - (r0 >> 1)) & 3);
  const int r1 = j1 >> 2, cc1 = (((j1 & 3) - (r1 >> 1)) & 3);

  const long a0 = (long)r0 * lda + cc0 * 8;
  const long a1 = (long)r1 * lda + cc1 * 8;
  const long b0 = (long)r0 * ldb + cc0 * 8;
  const long b1 = (long)r1 * ldb + cc1 * 8;

  int aoff[4], boff[4];
#pragma unroll
  for (int mt = 0; mt < 4; ++mt) {
    const int row = wm * 64 + mt * 16 + r16;
    aoff[mt] = row * 32 + (((row >> 1) + kq) & 3) * 8;
  }
#pragma unroll
  for (int nt = 0; nt < 4; ++nt) {
    const int row = wn * 64 + nt * 16 + r16;
    boff[nt] = row * 32 + (((row >> 1) + kq) & 3) * 8;
  }

  for (int k0 = 0; k0 < K; k0 += 32) {
    __syncthreads();
    async_copy16(A + a0 + k0, (char*)As + (w    ) * 1024);
    async_copy16(A + a1 + k0, (char*)As + (w + 4) * 1024);
    async_copy16(B + b0 + k0, (char*)Bs + (w    ) * 1024);
    async_copy16(B + b1 + k0, (char*)Bs + (w + 4) * 1024);
    __syncthreads();

    bf16x8 af[4], bg[4];
#pragma unroll
    for (int mt = 0; mt < 4; ++mt) af[mt] = *(const bf16x8*)&As[aoff[mt]];
#pragma unroll
    for (int nt = 0; nt < 4; ++nt) bg[nt] = *(const bf16x8*)&Bs[boff[nt]];
#pragma unroll
    for (int mt = 0; mt < 4; ++mt)
#pragma unroll
      for (int nt = 0; nt < 4; ++nt)
        acc[mt][nt] = __builtin_amdgcn_mfma_f32_16x16x32_bf16(af[mt], bg[nt], acc[mt][nt], 0, 0, 0);
  }
}

// ---------------- k_prep: casts + zeroing in ONE launch
__global__ __launch_bounds__(256) void k_prep(
    const float* __restrict__ X, const float* __restrict__ Wq, const float* __restrict__ Wk,
    unsigned short* __restrict__ Xbf, unsigned short* __restrict__ Wqb,
    unsigned short* __restrict__ Wkb, float* __restrict__ zp, float* __restrict__ out)
{
  const int blk = blockIdx.x;
  if (blk < 16384) {
    int i = (blk * 256 + threadIdx.x) * 4;
    float4 v = *(const float4*)(X + i);
    ushort4 o;
    o.x = f2bf(v.x); o.y = f2bf(v.y); o.z = f2bf(v.z); o.w = f2bf(v.w);
    *(ushort4*)(Xbf + i) = o;
  } else if (blk < 16896) {
    const int b2 = blk - 16384;
    const float* s = (b2 < 256) ? Wq : Wk;
    unsigned short* d = (b2 < 256) ? Wqb : Wkb;
    int i = ((b2 & 255) * 256 + threadIdx.x) * 4;
    float4 v = *(const float4*)(s + i);
    ushort4 o;
    o.x = f2bf(v.x); o.y = f2bf(v.y); o.z = f2bf(v.z); o.w = f2bf(v.w);
    *(ushort4*)(d + i) = o;
  } else {
    int i = (blk - 16896) * 256 + threadIdx.x;
    if (i < 65536) zp[i] = 0.0f;          // lrow + wcol
    else out[i - 65536] = 0.0f;           // 65536+8192 = 73728 = 288*256
  }
}

// ---------------- k_mt: Mt[e,d] = scale * sum_c Wk[e,c] Wq[d,c], 64x64 tiles
__global__ __launch_bounds__(256) void k_mt(
    const unsigned short* __restrict__ A, const unsigned short* __restrict__ B,
    unsigned short* __restrict__ C, float scale)
{
  __shared__ alignas(16) unsigned short As[64 * 32];
  __shared__ alignas(16) unsigned short Bs[64 * 32];
  f32x4 acc[2][2] = {};
  const int tid = threadIdx.x, lane = tid & 63, w = tid >> 6;
  const int wm = w >> 1, wn = w & 1, r16 = lane & 15, kq = lane >> 4;
  const long a0row = (long)blockIdx.y * 64, b0row = (long)blockIdx.x * 64;

  const int prow = tid >> 2, pslot = tid & 3, pc = (pslot - prow) & 3;
  const long asrc = (a0row + prow) * 512 + pc * 8;
  const long bsrc = (b0row + prow) * 512 + pc * 8;

  int aoff[2], boff[2];
#pragma unroll
  for (int t = 0; t < 2; ++t) {
    const int m = wm * 32 + t * 16 + r16;
    aoff[t] = m * 32 + ((m + kq) & 3) * 8;
    const int n = wn * 32 + t * 16 + r16;
    boff[t] = n * 32 + ((n + kq) & 3) * 8;
  }

  for (int k0 = 0; k0 < 512; k0 += 32) {
    __syncthreads();
    async_copy16(A + asrc + k0, (char*)As + w * 1024);
    async_copy16(B + bsrc + k0, (char*)Bs + w * 1024);
    __syncthreads();
    bf16x8 af[2], bg[2];
#pragma unroll
    for (int t = 0; t < 2; ++t) { af[t] = *(const bf16x8*)&As[aoff[t]]; bg[t] = *(const bf16x8*)&Bs[boff[t]]; }
#pragma unroll
    for (int mt = 0; mt < 2; ++mt)
#pragma unroll
      for (int nt = 0; nt < 2; ++nt)
        acc[mt][nt] = __builtin_amdgcn_mfma_f32_16x16x32_bf16(af[mt], bg[nt], acc[mt][nt], 0, 0, 0);
  }

  const int quad = lane >> 4;
#pragma unroll
  for (int mt = 0; mt < 2; ++mt)
#pragma unroll
    for (int nt = 0; nt < 2; ++nt)
#pragma unroll
      for (int r = 0; r < 4; ++r)
        C[(a0row + wm * 32 + mt * 16 + quad * 4 + r) * 512 + b0row + wn * 32 + nt * 16 + r16]
            = f2bf(acc[mt][nt][r] * scale);
}

// ---------------- Y-GEMM (XCD-swizzled): Y[i,e] = sum_d Xbf[i,d]*Mt[e,d]
__global__ __launch_bounds__(256) void k_ygemm(
    const unsigned short* __restrict__ A, const unsigned short* __restrict__ Mt,
    unsigned short* __restrict__ C)
{
  __shared__ alignas(16) unsigned short As[128 * 32];
  __shared__ alignas(16) unsigned short Bs[128 * 32];
  f32x4 acc[4][4] = {};
  // 1024 blocks; L%8 -> XCD; each XCD gets 32 consecutive row-tiles x 4 col-tiles
  const int L = blockIdx.x + (blockIdx.y << 2);
  const int xcd = L & 7, seq = L >> 3;          // seq 0..127
  const long am0 = (long)(xcd * 32 + (seq >> 2)) * 128;
  const long bn0 = (long)(seq & 3) * 128;
  gemm_core_nt(A + am0 * 512, 512, Mt + bn0 * 512, 512, 512, As, Bs, acc);

  const int lane = threadIdx.x & 63;
  const int w = threadIdx.x >> 6, wm = w >> 1, wn = w & 1;
  const long row0 = am0 + wm * 64 + (lane >> 4) * 4;
  const long col0 = bn0 + wn * 64 + (lane & 15);
#pragma unroll
  for (int mt = 0; mt < 4; ++mt)
#pragma unroll
    for (int nt = 0; nt < 4; ++nt)
#pragma unroll
      for (int r = 0; r < 4; ++r)
        C[(row0 + mt * 16 + r) * 512 + col0 + nt * 16] = f2bf(acc[mt][nt][r]);
}

// ---------------- pass A (16x16 core, XCD-swizzled): scores->exp2->row sums + fp8 E
union SMemAE {
  struct { unsigned short As[128 * 32]; unsigned short Bs[128 * 32]; } s;
  unsigned E32[128 * 36];   // [col][r4], stride-36 pad
};

__global__ __launch_bounds__(256) void k_passAE(
    const unsigned short* __restrict__ Ybf, const unsigned short* __restrict__ Xbf,
    float* __restrict__ lrow, unsigned* __restrict__ E)
{
  __shared__ SMemAE sm;
  f32x4 acc[4][4] = {};
  // 4096 blocks; L%8 -> XCD; each XCD streams 2 batches (Xb+Yb = 4MB = one L2)
  const int L = blockIdx.x + (blockIdx.y << 4) + (blockIdx.z << 8);
  const int xcd = L & 7, seq = L >> 3;          // seq 0..511
  const int b  = xcd * 2 + (seq >> 8);
  const int s2 = seq & 255;
  const int qt = s2 >> 4, kt = s2 & 15;
  const long q0 = (long)qt * 128;
  const long n0 = (long)kt * 128;
  gemm_core_nt(Ybf + ((long)b * S_LEN + q0) * D_DIM, D_DIM,
               Xbf + ((long)b * S_LEN + n0) * D_DIM, D_DIM, D_DIM,
               sm.s.As, sm.s.Bs, acc);

  const int lane = threadIdx.x & 63;
  const int w = threadIdx.x >> 6, wm = w >> 1, wn = w & 1;
  const int r16 = lane & 15, quad = lane >> 4;

  __syncthreads();   // all waves' ds_reads done before As/Bs reused as E32

#pragma unroll
  for (int mt = 0; mt < 4; ++mt) {
    float rs[4] = {0.f, 0.f, 0.f, 0.f};
#pragma unroll
    for (int nt = 0; nt < 4; ++nt) {
      float ev[4];
#pragma unroll
      for (int r = 0; r < 4; ++r) {
        ev[r] = __builtin_amdgcn_exp2f(acc[mt][nt][r]);
        rs[r] += ev[r];
      }
      const int col = wn * 64 + nt * 16 + r16;
      const int r4  = wm * 16 + mt * 4 + quad;
      sm.E32[col * 36 + r4] = pack4_fp8(ev[0], ev[1], ev[2], ev[3]);
    }
#pragma unroll
    for (int r = 0; r < 4; ++r) {
      float s = rs[r];
      s += __shfl_xor(s, 1, 64);
      s += __shfl_xor(s, 2, 64);
      s += __shfl_xor(s, 4, 64);
      s += __shfl_xor(s, 8, 64);
      if (r16 == 0)
        atomicAdd(&lrow[(long)b * S_LEN + q0 + wm * 64 + mt * 16 + quad * 4 + r], s);
    }
  }
  __syncthreads();

  unsigned* Eg = E + (((long)(b * 16 + qt)) * 16 + kt) * 4096;
  const int t = threadIdx.x;
#pragma unroll
  for (int p = 0; p < 4; ++p) {
    const int n = p * 256 + t;
    const int col = n >> 3, hj = n & 7;
    uint4 v = *(const uint4*)&sm.E32[col * 36 + hj * 4];
    *(uint4*)(Eg + n * 4) = v;
  }
}

// ---------------- w[b,k] += sum_q E[b,q,k]/l[b,q]  (tiled-layout, coalesced)
__global__ __launch_bounds__(256) void k_wsum(
    const unsigned* __restrict__ E, const float* __restrict__ lrow,
    float* __restrict__ wcol)
{
  __shared__ float rl[512];
  const int kt = blockIdx.x, qq = blockIdx.y, b = blockIdx.z;
  const int tid = threadIdx.x;
  {
    const float* lp = lrow + (long)b * S_LEN + qq * 512;
    rl[tid]       = 1.0f / lp[tid];
    rl[tid + 256] = 1.0f / lp[tid + 256];
  }
  __syncthreads();
  const int col = tid & 127, qsel = tid >> 7;
  float acc = 0.0f;
#pragma unroll
  for (int qt2 = 0; qt2 < 2; ++qt2) {
    const int qtl = qsel * 2 + qt2;
    const int qt = qq * 4 + qtl;
    const unsigned* Ep = E + (((long)(b * 16 + qt)) * 16 + kt) * 4096 + col * 32;
    const float* rlq = rl + qtl * 128;
#pragma unroll
    for (int j = 0; j < 8; ++j) {
      uint4 v = *(const uint4*)(Ep + j * 4);
      const unsigned dws[4] = {v.x, v.y, v.z, v.w};
#pragma unroll
      for (int i = 0; i < 4; ++i) {
        const unsigned dv = dws[i];
        const float* r = rlq + j * 16 + i * 4;
#if HAVE_FP8CVT
        acc += __builtin_amdgcn_cvt_f32_fp8((int)dv, 0) * r[0];
        acc += __builtin_amdgcn_cvt_f32_fp8((int)dv, 1) * r[1];
        acc += __builtin_amdgcn_cvt_f32_fp8((int)dv, 2) * r[2];
        acc += __builtin_amdgcn_cvt_f32_fp8((int)dv, 3) * r[3];
#else
        acc += dec8( dv        & 0xFFu) * r[0];
        acc += dec8((dv >>  8) & 0xFFu) * r[1];
        acc += dec8((dv >> 16) & 0xFFu) * r[2];
        acc += dec8((dv >> 24)        ) * r[3];
#endif
      }
    }
  }
  atomicAdd(&wcol[(long)b * S_LEN + kt * 128 + col], acc);
}

// ---------------- fallback pass A/B (no E; recompute) for small ws
__global__ __launch_bounds__(256) void k_passA(
    const unsigned short* __restrict__ Ybf, const unsigned short* __restrict__ Xbf,
    float* __restrict__ lrow)
{
  __shared__ alignas(16) unsigned short As[128 * 32];
  __shared__ alignas(16) unsigned short Bs[128 * 32];
  f32x4 acc[4][4] = {};
  const int b = blockIdx.z;
  const long q0 = (long)blockIdx.y * 128;
  const long n0 = (long)blockIdx.x * 128;
  gemm_core_nt(Ybf + ((long)b * S_LEN + q0) * D_DIM, D_DIM,
               Xbf + ((long)b * S_LEN + n0) * D_DIM, D_DIM, D_DIM, As, Bs, acc);

  const int lane = threadIdx.x & 63;
  const int w = threadIdx.x >> 6, wm = w >> 1;
#pragma unroll
  for (int mt = 0; mt < 4; ++mt) {
#pragma unroll
    for (int r = 0; r < 4; ++r) {
      float s = 0.0f;
#pragma unroll
      for (int nt = 0; nt < 4; ++nt) s += __builtin_amdgcn_exp2f(acc[mt][nt][r]);
      s += __shfl_xor(s, 1, 64);
      s += __shfl_xor(s, 2, 64);
      s += __shfl_xor(s, 4, 64);
      s += __shfl_xor(s, 8, 64);
      if ((lane & 15) == 0)
        atomicAdd(&lrow[(long)b * S_LEN + q0 + wm * 64 + mt * 16 + (lane >> 4) * 4 + r], s);
    }
  }
}

__global__ __launch_bounds__(256) void k_passB(
    const unsigned short* __restrict__ Ybf, const unsigned short* __restrict__ Xbf,
    const float* __restrict__ lrow, float* __restrict__ wcol)
{
  __shared__ alignas(16) unsigned short As[128 * 32];
  __shared__ alignas(16) unsigned short Bs[128 * 32];
  f32x4 acc[4][4] = {};
  const int b = blockIdx.z;
  const long q0 = (long)blockIdx.y * 128;
  const long n0 = (long)blockIdx.x * 128;
  gemm_core_nt(Ybf + ((long)b * S_LEN + q0) * D_DIM, D_DIM,
               Xbf + ((long)b * S_LEN + n0) * D_DIM, D_DIM, D_DIM, As, Bs, acc);

  const int lane = threadIdx.x & 63;
  const int w = threadIdx.x >> 6, wm = w >> 1, wn = w & 1;
  float csv[4] = {0.0f, 0.0f, 0.0f, 0.0f};
#pragma unroll
  for (int mt = 0; mt < 4; ++mt) {
    const float4 lv = *(const float4*)&lrow[(long)b * S_LEN + q0 + wm * 64 + mt * 16 + (lane >> 4) * 4];
    const float rv[4] = {1.0f / lv.x, 1.0f / lv.y, 1.0f / lv.z, 1.0f / lv.w};
#pragma unroll
    for (int nt = 0; nt < 4; ++nt)
#pragma unroll
      for (int r = 0; r < 4; ++r)
        csv[nt] += __builtin_amdgcn_exp2f(acc[mt][nt][r]) * rv[r];
  }
#pragma unroll
  for (int nt = 0; nt < 4; ++nt) {
    csv[nt] += __shfl_xor(csv[nt], 16, 64);
    csv[nt] += __shfl_xor(csv[nt], 32, 64);
  }
  if (lane < 16) {
#pragma unroll
    for (int nt = 0; nt < 4; ++nt)
      atomicAdd(&wcol[(long)b * S_LEN + n0 + wn * 64 + nt * 16 + lane], csv[nt]);
  }
}

// ---------------- tpart[p][b][d] = sum_{k chunk p} w[b,k]*X[b,k,d]  (ushort4, no atomics)
__global__ __launch_bounds__(256) void k_t(
    const unsigned short* __restrict__ Xbf, const float* __restrict__ wcol,
    float* __restrict__ tpart)
{
  const int b = blockIdx.z, kc = blockIdx.y;           // kc 0..31
  const int tid = threadIdx.x;
  const int c4 = tid & 127, ksel = tid >> 7;           // d = c4*4, k-half
  const int k0 = kc * 64 + ksel * 32;
  const int d = c4 * 4;
  const unsigned short* Xp = Xbf + ((long)b * S_LEN + k0) * D_DIM + d;
  const float* wp = wcol + (long)b * S_LEN + k0;
  float a0 = 0, a1 = 0, a2 = 0, a3 = 0;
#pragma unroll 8
  for (int k = 0; k < 32; ++k) {
    ushort4 xv = *(const ushort4*)(Xp + (long)k * D_DIM);
    const float wv = wp[k];
    a0 += wv * bf2f(xv.x); a1 += wv * bf2f(xv.y);
    a2 += wv * bf2f(xv.z); a3 += wv * bf2f(xv.w);
  }
  float4 o; o.x = a0; o.y = a1; o.z = a2; o.w = a3;
  *(float4*)&tpart[((long)(kc * 2 + ksel) * BATCH + b) * D_DIM + d] = o;
}

// ---------------- out[b,e] += sum_{d chunk} (sum_p tpart[p][b][d]) * Wv[d,e]
__global__ __launch_bounds__(128) void k_out(
    const float* __restrict__ tpart, const float* __restrict__ Wv, float* __restrict__ out)
{
  __shared__ float tl[128];
  const int b = blockIdx.y;
  const int d0 = blockIdx.z * 128;
  const int e = blockIdx.x * 128 + threadIdx.x;
  float tv = 0.0f;
#pragma unroll
  for (int p = 0; p < 64; ++p)
    tv += tpart[((long)p * BATCH + b) * D_DIM + d0 + threadIdx.x];
  tl[threadIdx.x] = tv;
  __syncthreads();
  float acc = 0.0f;
#pragma unroll 8
  for (int d = 0; d < 128; ++d) acc += tl[d] * Wv[(long)(d0 + d) * D_DIM + e];
  atomicAdd(&out[b * D_DIM + e], acc);
}

extern "C" void kernel_launch(void* const* d_in, const int* in_sizes, int n_in,
                              void* d_out, int out_size, void* d_ws, size_t ws_size,
                              hipStream_t stream) {
  const float* X  = (const float*)d_in[0];  // [16,2048,512]
  const float* Wq = (const float*)d_in[1];  // [512,512]
  const float* Wk = (const float*)d_in[2];
  const float* Wv = (const float*)d_in[3];
  float* out = (float*)d_out;               // [16,512]

  char* ws = (char*)d_ws;
  unsigned short* Xbf = (unsigned short*)(ws);              // 32 MB
  unsigned short* Ybf = (unsigned short*)(ws + 33554432);   // 32 MB
  unsigned short* Mt  = (unsigned short*)(ws + 67108864);   // 512 KB
  unsigned short* Wqb = (unsigned short*)(ws + 67633152);   // 512 KB
  unsigned short* Wkb = (unsigned short*)(ws + 68157440);   // 512 KB
  float* lrow = (float*)(ws + 68681728);                    // 128 KB  l[b,q]
  float* wcol = (float*)(ws + 68812800);                    // 128 KB  w[b,k]
  unsigned* E = (unsigned*)(ws + 69206016);                 // 64 MB   fp8 E, tiled
  // tpart aliases Ybf (dead after passAE): 64*16*512 fp32 = 2 MB
  float* tpart = (float*)(ws + 33554432);
  const bool bigws = ws_size >= (size_t)69206016 + (size_t)67108864;

  // one launch: cast X, cast Wq/Wk, zero lrow/wcol + out
  k_prep<<<17184, 256, 0, stream>>>(X, Wq, Wk, Xbf, Wqb, Wkb, lrow, out);

  // Mt[e,d] = (log2(e)/sqrt(512)) * sum_c Wk[e,c] Wq[d,c]
  const float scale = 1.4426950408889634f / 22.627416997969522f;
  k_mt<<<dim3(8, 8), 256, 0, stream>>>(Wkb, Wqb, Mt, scale);

  // Y[i,e] = sum_d Xbf[i,d] * Mt[e,d]  (XCD-swizzled)
  k_ygemm<<<dim3(4, 256), 256, 0, stream>>>(Xbf, Mt, Ybf);

  if (bigws) {
    k_passAE<<<dim3(16, 16, 16), 256, 0, stream>>>(Ybf, Xbf, lrow, E);
    k_wsum<<<dim3(16, 4, 16), 256, 0, stream>>>(E, lrow, wcol);
  } else {
    k_passA<<<dim3(16, 16, 16), 256, 0, stream>>>(Ybf, Xbf, lrow);
    k_passB<<<dim3(16, 16, 16), 256, 0, stream>>>(Ybf, Xbf, lrow, wcol);
  }

  // tpart = w @ X (ushort4, no atomics), out = (sum tpart) @ Wv
  k_t<<<dim3(1, 32, 16), 256, 0, stream>>>(Xbf, wcol, tpart);
  k_out<<<dim3(4, 16, 4), 128, 0, stream>>>(tpart, Wv, out);
}

// Round 8
// 287.482 us; speedup vs baseline: 1.0765x; 1.0765x over previous
//
#include <hip/hip_runtime.h>
#include <hip/hip_bf16.h>

// B=16, S=2048, D=512 attention with sum-pool over queries.
// out[b] = ((sum_q softmax(X M X^T * scale)[q,:]) @ X_b) @ Wv,  M = Wq Wk^T.
// log2(e)/sqrt(D) folded into M so exponentials are native exp2.
// E = exp2(scores) stored fp8 (HW e4m3), tiled [b][qt][kt][col128][row4(32)].
//
// Experiment log (measured):
//  - 16x16x32 core, BK=32, rotate swizzle: passAE 111us, VGPR 76, occ 30%. BEST.
//  - BK=64: occ 30->21%, 125us. REGRESSED.
//  - 32x32x16 core: 11.5M LDS conflicts (even rows hit 2/8 bank groups), 139us. REGRESSED.
//  - XCD swizzle (batch-per-XCD): FETCH 144->55MB but 147us — passAE is NOT
//    fetch-bound; locality does not help. REGRESSED. Plain dispatch restored.

#define S_LEN 2048
#define D_DIM 512
#define BATCH 16

typedef short bf16x8 __attribute__((ext_vector_type(8)));
typedef float f32x4 __attribute__((ext_vector_type(4)));

typedef __attribute__((address_space(3))) void lds_void_t;
typedef const __attribute__((address_space(1))) void gbl_void_t;

__device__ __forceinline__ void async_copy16(const void* g, void* l) {
  __builtin_amdgcn_global_load_lds((gbl_void_t*)g, (lds_void_t*)l, 16, 0, 0);
}

__device__ __forceinline__ unsigned short f2bf(float f) {
  unsigned u = __float_as_uint(f);
  u += 0x7fff + ((u >> 16) & 1);   // RNE
  return (unsigned short)(u >> 16);
}
__device__ __forceinline__ float bf2f(unsigned short h) {
  return __uint_as_float((unsigned)h << 16);
}

#if __has_builtin(__builtin_amdgcn_cvt_pk_fp8_f32) && __has_builtin(__builtin_amdgcn_cvt_f32_fp8)
#define HAVE_FP8CVT 1
#else
#define HAVE_FP8CVT 0
#endif

__device__ __forceinline__ unsigned enc8(float x) {
  unsigned u = __float_as_uint(x);
  unsigned t = (u + 0x7FFFFu + ((u >> 20) & 1u)) >> 20;
  int b = (int)t - 0x3C0;
  b = b < 0 ? 0 : (b > 127 ? 127 : b);
  return (unsigned)b;
}
__device__ __forceinline__ float dec8(unsigned b) {
  return b ? __uint_as_float((b + 0x3C0u) << 20) : 0.0f;
}

__device__ __forceinline__ unsigned pack4_fp8(float e0, float e1, float e2, float e3) {
#if HAVE_FP8CVT
  unsigned dw = (unsigned)__builtin_amdgcn_cvt_pk_fp8_f32(e0, e1, 0, false);
  dw = (unsigned)__builtin_amdgcn_cvt_pk_fp8_f32(e2, e3, (int)dw, true);
  return dw;
#else
  return enc8(e0) | (enc8(e1) << 8) | (enc8(e2) << 16) | (enc8(e3) << 24);
#endif
}

// ---------------- NT GEMM core (16x16x32): C(128x128) = A*B^T, bf16, fp32 acc.
// BK=32, rotate swizzle -> ds_read_b128 conflict-free (verified: 0 core conflicts).
__device__ __forceinline__ void gemm_core_nt(
    const unsigned short* __restrict__ A, long lda,
    const unsigned short* __restrict__ B, long ldb,
    int K, unsigned short* As, unsigned short* Bs, f32x4 acc[4][4])
{
  const int tid  = threadIdx.x;
  const int lane = tid & 63;
  const int w    = tid >> 6;
  const int wm   = w >> 1, wn = w & 1;
  const int r16  = lane & 15;
  const int kq   = lane >> 4;

  const int j0 = w * 64 + lane;
  const int j1 = (w + 4) * 64 + lane;
  const int r0 = j0 >> 2, cc0 = (((j0 & 3) - (r0 >> 1)) & 3);
  const int r1 = j1 >> 2, cc1 = (((j1 & 3) - (r1 >> 1)) & 3);

  const long a0 = (long)r0 * lda + cc0 * 8;
  const long a1 = (long)r1 * lda + cc1 * 8;
  const long b0 = (long)r0 * ldb + cc0 * 8;
  const long b1 = (long)r1 * ldb + cc1 * 8;

  int aoff[4], boff[4];
#pragma unroll
  for (int mt = 0; mt < 4; ++mt) {
    const int row = wm * 64 + mt * 16 + r16;
    aoff[mt] = row * 32 + (((row >> 1) + kq) & 3) * 8;
  }
#pragma unroll
  for (int nt = 0; nt < 4; ++nt) {
    const int row = wn * 64 + nt * 16 + r16;
    boff[nt] = row * 32 + (((row >> 1) + kq) & 3) * 8;
  }

  for (int k0 = 0; k0 < K; k0 += 32) {
    __syncthreads();
    async_copy16(A + a0 + k0, (char*)As + (w    ) * 1024);
    async_copy16(A + a1 + k0, (char*)As + (w + 4) * 1024);
    async_copy16(B + b0 + k0, (char*)Bs + (w    ) * 1024);
    async_copy16(B + b1 + k0, (char*)Bs + (w + 4) * 1024);
    __syncthreads();

    bf16x8 af[4], bg[4];
#pragma unroll
    for (int mt = 0; mt < 4; ++mt) af[mt] = *(const bf16x8*)&As[aoff[mt]];
#pragma unroll
    for (int nt = 0; nt < 4; ++nt) bg[nt] = *(const bf16x8*)&Bs[boff[nt]];
#pragma unroll
    for (int mt = 0; mt < 4; ++mt)
#pragma unroll
      for (int nt = 0; nt < 4; ++nt)
        acc[mt][nt] = __builtin_amdgcn_mfma_f32_16x16x32_bf16(af[mt], bg[nt], acc[mt][nt], 0, 0, 0);
  }
}

// ---------------- k_prep: casts + zeroing in ONE launch
__global__ __launch_bounds__(256) void k_prep(
    const float* __restrict__ X, const float* __restrict__ Wq, const float* __restrict__ Wk,
    unsigned short* __restrict__ Xbf, unsigned short* __restrict__ Wqb,
    unsigned short* __restrict__ Wkb, float* __restrict__ zp, float* __restrict__ out)
{
  const int blk = blockIdx.x;
  if (blk < 16384) {
    int i = (blk * 256 + threadIdx.x) * 4;
    float4 v = *(const float4*)(X + i);
    ushort4 o;
    o.x = f2bf(v.x); o.y = f2bf(v.y); o.z = f2bf(v.z); o.w = f2bf(v.w);
    *(ushort4*)(Xbf + i) = o;
  } else if (blk < 16896) {
    const int b2 = blk - 16384;
    const float* s = (b2 < 256) ? Wq : Wk;
    unsigned short* d = (b2 < 256) ? Wqb : Wkb;
    int i = ((b2 & 255) * 256 + threadIdx.x) * 4;
    float4 v = *(const float4*)(s + i);
    ushort4 o;
    o.x = f2bf(v.x); o.y = f2bf(v.y); o.z = f2bf(v.z); o.w = f2bf(v.w);
    *(ushort4*)(d + i) = o;
  } else {
    int i = (blk - 16896) * 256 + threadIdx.x;
    if (i < 65536) zp[i] = 0.0f;          // lrow + wcol
    else out[i - 65536] = 0.0f;           // 65536+8192 = 73728 = 288*256
  }
}

// ---------------- k_mt: Mt[e,d] = scale * sum_c Wk[e,c] Wq[d,c], 64x64 tiles
__global__ __launch_bounds__(256) void k_mt(
    const unsigned short* __restrict__ A, const unsigned short* __restrict__ B,
    unsigned short* __restrict__ C, float scale)
{
  __shared__ alignas(16) unsigned short As[64 * 32];
  __shared__ alignas(16) unsigned short Bs[64 * 32];
  f32x4 acc[2][2] = {};
  const int tid = threadIdx.x, lane = tid & 63, w = tid >> 6;
  const int wm = w >> 1, wn = w & 1, r16 = lane & 15, kq = lane >> 4;
  const long a0row = (long)blockIdx.y * 64, b0row = (long)blockIdx.x * 64;

  const int prow = tid >> 2, pslot = tid & 3, pc = (pslot - prow) & 3;
  const long asrc = (a0row + prow) * 512 + pc * 8;
  const long bsrc = (b0row + prow) * 512 + pc * 8;

  int aoff[2], boff[2];
#pragma unroll
  for (int t = 0; t < 2; ++t) {
    const int m = wm * 32 + t * 16 + r16;
    aoff[t] = m * 32 + ((m + kq) & 3) * 8;
    const int n = wn * 32 + t * 16 + r16;
    boff[t] = n * 32 + ((n + kq) & 3) * 8;
  }

  for (int k0 = 0; k0 < 512; k0 += 32) {
    __syncthreads();
    async_copy16(A + asrc + k0, (char*)As + w * 1024);
    async_copy16(B + bsrc + k0, (char*)Bs + w * 1024);
    __syncthreads();
    bf16x8 af[2], bg[2];
#pragma unroll
    for (int t = 0; t < 2; ++t) { af[t] = *(const bf16x8*)&As[aoff[t]]; bg[t] = *(const bf16x8*)&Bs[boff[t]]; }
#pragma unroll
    for (int mt = 0; mt < 2; ++mt)
#pragma unroll
      for (int nt = 0; nt < 2; ++nt)
        acc[mt][nt] = __builtin_amdgcn_mfma_f32_16x16x32_bf16(af[mt], bg[nt], acc[mt][nt], 0, 0, 0);
  }

  const int quad = lane >> 4;
#pragma unroll
  for (int mt = 0; mt < 2; ++mt)
#pragma unroll
    for (int nt = 0; nt < 2; ++nt)
#pragma unroll
      for (int r = 0; r < 4; ++r)
        C[(a0row + wm * 32 + mt * 16 + quad * 4 + r) * 512 + b0row + wn * 32 + nt * 16 + r16]
            = f2bf(acc[mt][nt][r] * scale);
}

// ---------------- Y-GEMM (plain dispatch): Y[i,e] = sum_d Xbf[i,d]*Mt[e,d]
__global__ __launch_bounds__(256) void k_gemm_bf16out(
    const unsigned short* __restrict__ A, long lda,
    const unsigned short* __restrict__ B, long ldb, int K,
    unsigned short* __restrict__ C, long ldc, float scale)
{
  __shared__ alignas(16) unsigned short As[128 * 32];
  __shared__ alignas(16) unsigned short Bs[128 * 32];
  f32x4 acc[4][4] = {};
  const long am0 = (long)blockIdx.y * 128;
  const long bn0 = (long)blockIdx.x * 128;
  gemm_core_nt(A + am0 * lda, lda, B + bn0 * ldb, ldb, K, As, Bs, acc);

  const int lane = threadIdx.x & 63;
  const int w = threadIdx.x >> 6, wm = w >> 1, wn = w & 1;
  const long row0 = am0 + wm * 64 + (lane >> 4) * 4;
  const long col0 = bn0 + wn * 64 + (lane & 15);
#pragma unroll
  for (int mt = 0; mt < 4; ++mt)
#pragma unroll
    for (int nt = 0; nt < 4; ++nt)
#pragma unroll
      for (int r = 0; r < 4; ++r)
        C[(row0 + mt * 16 + r) * ldc + col0 + nt * 16] = f2bf(acc[mt][nt][r] * scale);
}

// ---------------- pass A (plain dispatch): scores -> exp2 -> row sums + fp8 E
union SMemAE {
  struct { unsigned short As[128 * 32]; unsigned short Bs[128 * 32]; } s;
  unsigned E32[128 * 36];   // [col][r4], stride-36 pad
};

__global__ __launch_bounds__(256) void k_passAE(
    const unsigned short* __restrict__ Ybf, const unsigned short* __restrict__ Xbf,
    float* __restrict__ lrow, unsigned* __restrict__ E)
{
  __shared__ SMemAE sm;
  f32x4 acc[4][4] = {};
  const int b = blockIdx.z, qt = blockIdx.y, kt = blockIdx.x;
  const long q0 = (long)qt * 128;
  const long n0 = (long)kt * 128;
  gemm_core_nt(Ybf + ((long)b * S_LEN + q0) * D_DIM, D_DIM,
               Xbf + ((long)b * S_LEN + n0) * D_DIM, D_DIM, D_DIM,
               sm.s.As, sm.s.Bs, acc);

  const int lane = threadIdx.x & 63;
  const int w = threadIdx.x >> 6, wm = w >> 1, wn = w & 1;
  const int r16 = lane & 15, quad = lane >> 4;

  __syncthreads();   // all waves' ds_reads done before As/Bs reused as E32

#pragma unroll
  for (int mt = 0; mt < 4; ++mt) {
    float rs[4] = {0.f, 0.f, 0.f, 0.f};
#pragma unroll
    for (int nt = 0; nt < 4; ++nt) {
      float ev[4];
#pragma unroll
      for (int r = 0; r < 4; ++r) {
        ev[r] = __builtin_amdgcn_exp2f(acc[mt][nt][r]);
        rs[r] += ev[r];
      }
      const int col = wn * 64 + nt * 16 + r16;
      const int r4  = wm * 16 + mt * 4 + quad;
      sm.E32[col * 36 + r4] = pack4_fp8(ev[0], ev[1], ev[2], ev[3]);
    }
#pragma unroll
    for (int r = 0; r < 4; ++r) {
      float s = rs[r];
      s += __shfl_xor(s, 1, 64);
      s += __shfl_xor(s, 2, 64);
      s += __shfl_xor(s, 4, 64);
      s += __shfl_xor(s, 8, 64);
      if (r16 == 0)
        atomicAdd(&lrow[(long)b * S_LEN + q0 + wm * 64 + mt * 16 + quad * 4 + r], s);
    }
  }
  __syncthreads();

  unsigned* Eg = E + (((long)(b * 16 + qt)) * 16 + kt) * 4096;
  const int t = threadIdx.x;
#pragma unroll
  for (int p = 0; p < 4; ++p) {
    const int n = p * 256 + t;
    const int col = n >> 3, hj = n & 7;
    uint4 v = *(const uint4*)&sm.E32[col * 36 + hj * 4];
    *(uint4*)(Eg + n * 4) = v;
  }
}

// ---------------- w[b,k] += sum_q E[b,q,k]/l[b,q]  (tiled-layout, coalesced)
__global__ __launch_bounds__(256) void k_wsum(
    const unsigned* __restrict__ E, const float* __restrict__ lrow,
    float* __restrict__ wcol)
{
  __shared__ float rl[512];
  const int kt = blockIdx.x, qq = blockIdx.y, b = blockIdx.z;
  const int tid = threadIdx.x;
  {
    const float* lp = lrow + (long)b * S_LEN + qq * 512;
    rl[tid]       = 1.0f / lp[tid];
    rl[tid + 256] = 1.0f / lp[tid + 256];
  }
  __syncthreads();
  const int col = tid & 127, qsel = tid >> 7;
  float acc = 0.0f;
#pragma unroll
  for (int qt2 = 0; qt2 < 2; ++qt2) {
    const int qtl = qsel * 2 + qt2;
    const int qt = qq * 4 + qtl;
    const unsigned* Ep = E + (((long)(b * 16 + qt)) * 16 + kt) * 4096 + col * 32;
    const float* rlq = rl + qtl * 128;
#pragma unroll
    for (int j = 0; j < 8; ++j) {
      uint4 v = *(const uint4*)(Ep + j * 4);
      const unsigned dws[4] = {v.x, v.y, v.z, v.w};
#pragma unroll
      for (int i = 0; i < 4; ++i) {
        const unsigned dv = dws[i];
        const float* r = rlq + j * 16 + i * 4;
#if HAVE_FP8CVT
        acc += __builtin_amdgcn_cvt_f32_fp8((int)dv, 0) * r[0];
        acc += __builtin_amdgcn_cvt_f32_fp8((int)dv, 1) * r[1];
        acc += __builtin_amdgcn_cvt_f32_fp8((int)dv, 2) * r[2];
        acc += __builtin_amdgcn_cvt_f32_fp8((int)dv, 3) * r[3];
#else
        acc += dec8( dv        & 0xFFu) * r[0];
        acc += dec8((dv >>  8) & 0xFFu) * r[1];
        acc += dec8((dv >> 16) & 0xFFu) * r[2];
        acc += dec8((dv >> 24)        ) * r[3];
#endif
      }
    }
  }
  atomicAdd(&wcol[(long)b * S_LEN + kt * 128 + col], acc);
}

// ---------------- fallback pass A/B (no E; recompute) for small ws
__global__ __launch_bounds__(256) void k_passA(
    const unsigned short* __restrict__ Ybf, const unsigned short* __restrict__ Xbf,
    float* __restrict__ lrow)
{
  __shared__ alignas(16) unsigned short As[128 * 32];
  __shared__ alignas(16) unsigned short Bs[128 * 32];
  f32x4 acc[4][4] = {};
  const int b = blockIdx.z;
  const long q0 = (long)blockIdx.y * 128;
  const long n0 = (long)blockIdx.x * 128;
  gemm_core_nt(Ybf + ((long)b * S_LEN + q0) * D_DIM, D_DIM,
               Xbf + ((long)b * S_LEN + n0) * D_DIM, D_DIM, D_DIM, As, Bs, acc);

  const int lane = threadIdx.x & 63;
  const int w = threadIdx.x >> 6, wm = w >> 1;
#pragma unroll
  for (int mt = 0; mt < 4; ++mt) {
#pragma unroll
    for (int r = 0; r < 4; ++r) {
      float s = 0.0f;
#pragma unroll
      for (int nt = 0; nt < 4; ++nt) s += __builtin_amdgcn_exp2f(acc[mt][nt][r]);
      s += __shfl_xor(s, 1, 64);
      s += __shfl_xor(s, 2, 64);
      s += __shfl_xor(s, 4, 64);
      s += __shfl_xor(s, 8, 64);
      if ((lane & 15) == 0)
        atomicAdd(&lrow[(long)b * S_LEN + q0 + wm * 64 + mt * 16 + (lane >> 4) * 4 + r], s);
    }
  }
}

__global__ __launch_bounds__(256) void k_passB(
    const unsigned short* __restrict__ Ybf, const unsigned short* __restrict__ Xbf,
    const float* __restrict__ lrow, float* __restrict__ wcol)
{
  __shared__ alignas(16) unsigned short As[128 * 32];
  __shared__ alignas(16) unsigned short Bs[128 * 32];
  f32x4 acc[4][4] = {};
  const int b = blockIdx.z;
  const long q0 = (long)blockIdx.y * 128;
  const long n0 = (long)blockIdx.x * 128;
  gemm_core_nt(Ybf + ((long)b * S_LEN + q0) * D_DIM, D_DIM,
               Xbf + ((long)b * S_LEN + n0) * D_DIM, D_DIM, D_DIM, As, Bs, acc);

  const int lane = threadIdx.x & 63;
  const int w = threadIdx.x >> 6, wm = w >> 1, wn = w & 1;
  float csv[4] = {0.0f, 0.0f, 0.0f, 0.0f};
#pragma unroll
  for (int mt = 0; mt < 4; ++mt) {
    const float4 lv = *(const float4*)&lrow[(long)b * S_LEN + q0 + wm * 64 + mt * 16 + (lane >> 4) * 4];
    const float rv[4] = {1.0f / lv.x, 1.0f / lv.y, 1.0f / lv.z, 1.0f / lv.w};
#pragma unroll
    for (int nt = 0; nt < 4; ++nt)
#pragma unroll
      for (int r = 0; r < 4; ++r)
        csv[nt] += __builtin_amdgcn_exp2f(acc[mt][nt][r]) * rv[r];
  }
#pragma unroll
  for (int nt = 0; nt < 4; ++nt) {
    csv[nt] += __shfl_xor(csv[nt], 16, 64);
    csv[nt] += __shfl_xor(csv[nt], 32, 64);
  }
  if (lane < 16) {
#pragma unroll
    for (int nt = 0; nt < 4; ++nt)
      atomicAdd(&wcol[(long)b * S_LEN + n0 + wn * 64 + nt * 16 + lane], csv[nt]);
  }
}

// ---------------- tpart[p][b][d] = sum_{k chunk p} w[b,k]*X[b,k,d]  (ushort4, no atomics)
__global__ __launch_bounds__(256) void k_t(
    const unsigned short* __restrict__ Xbf, const float* __restrict__ wcol,
    float* __restrict__ tpart)
{
  const int b = blockIdx.z, kc = blockIdx.y;           // kc 0..31
  const int tid = threadIdx.x;
  const int c4 = tid & 127, ksel = tid >> 7;           // d = c4*4, k-half
  const int k0 = kc * 64 + ksel * 32;
  const int d = c4 * 4;
  const unsigned short* Xp = Xbf + ((long)b * S_LEN + k0) * D_DIM + d;
  const float* wp = wcol + (long)b * S_LEN + k0;
  float a0 = 0, a1 = 0, a2 = 0, a3 = 0;
#pragma unroll 8
  for (int k = 0; k < 32; ++k) {
    ushort4 xv = *(const ushort4*)(Xp + (long)k * D_DIM);
    const float wv = wp[k];
    a0 += wv * bf2f(xv.x); a1 += wv * bf2f(xv.y);
    a2 += wv * bf2f(xv.z); a3 += wv * bf2f(xv.w);
  }
  float4 o; o.x = a0; o.y = a1; o.z = a2; o.w = a3;
  *(float4*)&tpart[((long)(kc * 2 + ksel) * BATCH + b) * D_DIM + d] = o;
}

// ---------------- out[b,e] += sum_{d chunk} (sum_p tpart[p][b][d]) * Wv[d,e]
__global__ __launch_bounds__(128) void k_out(
    const float* __restrict__ tpart, const float* __restrict__ Wv, float* __restrict__ out)
{
  __shared__ float tl[128];
  const int b = blockIdx.y;
  const int d0 = blockIdx.z * 128;
  const int e = blockIdx.x * 128 + threadIdx.x;
  float tv = 0.0f;
#pragma unroll
  for (int p = 0; p < 64; ++p)
    tv += tpart[((long)p * BATCH + b) * D_DIM + d0 + threadIdx.x];
  tl[threadIdx.x] = tv;
  __syncthreads();
  float acc = 0.0f;
#pragma unroll 8
  for (int d = 0; d < 128; ++d) acc += tl[d] * Wv[(long)(d0 + d) * D_DIM + e];
  atomicAdd(&out[b * D_DIM + e], acc);
}

extern "C" void kernel_launch(void* const* d_in, const int* in_sizes, int n_in,
                              void* d_out, int out_size, void* d_ws, size_t ws_size,
                              hipStream_t stream) {
  const float* X  = (const float*)d_in[0];  // [16,2048,512]
  const float* Wq = (const float*)d_in[1];  // [512,512]
  const float* Wk = (const float*)d_in[2];
  const float* Wv = (const float*)d_in[3];
  float* out = (float*)d_out;               // [16,512]

  char* ws = (char*)d_ws;
  unsigned short* Xbf = (unsigned short*)(ws);              // 32 MB
  unsigned short* Ybf = (unsigned short*)(ws + 33554432);   // 32 MB
  unsigned short* Mt  = (unsigned short*)(ws + 67108864);   // 512 KB
  unsigned short* Wqb = (unsigned short*)(ws + 67633152);   // 512 KB
  unsigned short* Wkb = (unsigned short*)(ws + 68157440);   // 512 KB
  float* lrow = (float*)(ws + 68681728);                    // 128 KB  l[b,q]
  float* wcol = (float*)(ws + 68812800);                    // 128 KB  w[b,k]
  unsigned* E = (unsigned*)(ws + 69206016);                 // 64 MB   fp8 E, tiled
  // tpart aliases Ybf (dead after passAE): 64*16*512 fp32 = 2 MB
  float* tpart = (float*)(ws + 33554432);
  const bool bigws = ws_size >= (size_t)69206016 + (size_t)67108864;

  // one launch: cast X, cast Wq/Wk, zero lrow/wcol + out
  k_prep<<<17184, 256, 0, stream>>>(X, Wq, Wk, Xbf, Wqb, Wkb, lrow, out);

  // Mt[e,d] = (log2(e)/sqrt(512)) * sum_c Wk[e,c] Wq[d,c]
  const float scale = 1.4426950408889634f / 22.627416997969522f;
  k_mt<<<dim3(8, 8), 256, 0, stream>>>(Wkb, Wqb, Mt, scale);

  // Y[i,e] = sum_d Xbf[i,d] * Mt[e,d]
  k_gemm_bf16out<<<dim3(4, 256), 256, 0, stream>>>(Xbf, 512, Mt, 512, 512, Ybf, 512, 1.0f);

  if (bigws) {
    k_passAE<<<dim3(16, 16, 16), 256, 0, stream>>>(Ybf, Xbf, lrow, E);
    k_wsum<<<dim3(16, 4, 16), 256, 0, stream>>>(E, lrow, wcol);
  } else {
    k_passA<<<dim3(16, 16, 16), 256, 0, stream>>>(Ybf, Xbf, lrow);
    k_passB<<<dim3(16, 16, 16), 256, 0, stream>>>(Ybf, Xbf, lrow, wcol);
  }

  // tpart = w @ X (ushort4, no atomics), out = (sum tpart) @ Wv
  k_t<<<dim3(1, 32, 16), 256, 0, stream>>>(Xbf, wcol, tpart);
  k_out<<<dim3(4, 16, 4), 128, 0, stream>>>(tpart, Wv, out);
}